// Round 9
// baseline (74.192 us; speedup 1.0000x reference)
//
#include <hip/hip_runtime.h>

// Path signature, depth 4, C=8, L=256, N=256 — time-segmented, LDS-pipe-relieved.
// One block (1024 thr = 16 waves) per sample; 4 groups of 256 threads run the
// factored Chen recursion on a 64/64/64/63 segment; 3 Chen combines in LDS.
//
// R7 post-mortem: kernel was LDS-pipe-bound (~44 LDS-cy/wave-iter x 16 waves
// ~= 700 cy/iter vs 248 VALU). This version keeps only the 2 broadcast
// ds_read_b128 (vv[0..7]) and replaces the 3 indexed LDS reads (v[i],v[j],
// v[k0],v[k0+1]) with v_cndmask select trees on loop-invariant masks:
// -3 DS ops, +20 VALU per iter -> LDS 384 cy/iter-slot, VALU ~408. ~2x.

constexpr int N_SAMP = 256;
constexpr int L_LEN = 256;
constexpr int C_DIM = 8;
constexpr int OUT_PER = 8 + 64 + 512 + 4096; // 4680
constexpr int NSEG = 4;
constexpr int SIG_STRIDE = 4688; // 4680 padded

__global__ __launch_bounds__(1024) void sig_kernel(const float* __restrict__ path,
                                                   float* __restrict__ out) {
    __shared__ float dx[(L_LEN - 1) * C_DIM];   // 2040 floats
    __shared__ float sig[NSEG][SIG_STRIDE];     // 4*4688 floats = 75 KB

    const int n = blockIdx.x;
    const int tid = threadIdx.x;

    // ---- stage increments into LDS (1020 float2's) ----
    const float* p = path + (size_t)n * L_LEN * C_DIM;
    if (tid < 1020) {
        float2 a = *(const float2*)(p + tid * 2);
        float2 b = *(const float2*)(p + tid * 2 + C_DIM);
        *(float2*)(&dx[tid * 2]) = make_float2(b.x - a.x, b.y - a.y);
    }
    __syncthreads();

    // ---- phase 1: per-segment recursion ----
    const int seg = tid >> 8;      // 0..3
    const int r = tid & 255;
    const int i = r >> 5;
    const int j = (r >> 2) & 7;
    const int k0 = (r & 3) * 2;

    const int t0 = seg * 64;
    const int tcnt = (seg == 3) ? 63 : 64;   // wave-uniform

    // loop-invariant selection masks (hoisted v_cmp -> saved 64b masks)
    const bool ib0 = (i & 1), ib1 = (i & 2), ib2 = (i & 4);
    const bool jb0 = (j & 1), jb1 = (j & 2), jb2 = (j & 4);
    const bool kb0 = (r & 1), kb1 = (r & 2);

    float acc[16];
#pragma unroll
    for (int m = 0; m < 16; ++m) acc[m] = 0.f;
    float s3a = 0.f, s3b = 0.f, s2 = 0.f, s1 = 0.f;

    constexpr float THIRD = 1.f / 3.f;

#pragma unroll 4
    for (int t = 0; t < tcnt; ++t) {
        const float* v = &dx[(t0 + t) * C_DIM];
        float vv[8];
#pragma unroll
        for (int c = 0; c < 8; ++c) vv[c] = v[c]; // 2x ds_read_b128 (broadcast)

        // vi = vv[i] via cndmask tree (i loop-invariant)
        float si01 = ib0 ? vv[1] : vv[0];
        float si23 = ib0 ? vv[3] : vv[2];
        float si45 = ib0 ? vv[5] : vv[4];
        float si67 = ib0 ? vv[7] : vv[6];
        float si03 = ib1 ? si23 : si01;
        float si47 = ib1 ? si67 : si45;
        float vi = ib2 ? si47 : si03;

        // vj = vv[j]
        float sj01 = jb0 ? vv[1] : vv[0];
        float sj23 = jb0 ? vv[3] : vv[2];
        float sj45 = jb0 ? vv[5] : vv[4];
        float sj67 = jb0 ? vv[7] : vv[6];
        float sj03 = jb1 ? sj23 : sj01;
        float sj47 = jb1 ? sj67 : sj45;
        float vj = jb2 ? sj47 : sj03;

        // (vk0, vk1) = (vv[k0], vv[k0+1]), pair index = r&3
        float a01 = kb0 ? vv[2] : vv[0];
        float a23 = kb0 ? vv[6] : vv[4];
        float vk0 = kb1 ? a23 : a01;
        float b01 = kb0 ? vv[3] : vv[1];
        float b23 = kb0 ? vv[7] : vv[5];
        float vk1 = kb1 ? b23 : b01;

        // factored Chen coefficients (all use OLD s1,s2,s3)
        float c4 = fmaf(vj * THIRD, fmaf(0.25f, vi, s1), s2);
        float c3 = fmaf(vj * 0.5f, fmaf(THIRD, vi, s1), s2);
        float f0 = fmaf(c4, 0.5f * vk0, s3a);
        float f1 = fmaf(c4, 0.5f * vk1, s3b);

#pragma unroll
        for (int l = 0; l < 8; ++l) {
            acc[l] = fmaf(f0, vv[l], acc[l]);
            acc[8 + l] = fmaf(f1, vv[l], acc[8 + l]);
        }
        s3a = fmaf(c3, vk0, s3a);
        s3b = fmaf(c3, vk1, s3b);
        s2 = fmaf(fmaf(0.5f, vi, s1), vj, s2);
        s1 += vi;
    }

    // ---- store segment signature to LDS ----
    {
        float* sg = sig[seg];
        if ((r & 31) == 0) sg[i] = s1;
        if ((r & 3) == 0) sg[8 + i * 8 + j] = s2;
        *(float2*)(&sg[72 + r * 2]) = make_float2(s3a, s3b);
        float* s4 = sg + 584 + r * 16;
        *(float4*)(s4) = make_float4(acc[0], acc[1], acc[2], acc[3]);
        *(float4*)(s4 + 4) = make_float4(acc[4], acc[5], acc[6], acc[7]);
        *(float4*)(s4 + 8) = make_float4(acc[8], acc[9], acc[10], acc[11]);
        *(float4*)(s4 + 12) = make_float4(acc[12], acc[13], acc[14], acc[15]);
    }
    __syncthreads();

    // ---- phase 2: 3 sequential Chen combines, result accumulates in sig[0] ----
    const int i4 = tid >> 7;
    const int j4 = (tid >> 4) & 7;
    const int k4 = (tid >> 1) & 7;
    const int l0 = (tid & 1) * 4;
    const int ijk4 = tid >> 1;

    for (int b = 1; b < NSEG; ++b) {
        const float* A = sig[0];
        const float* B = sig[b];

        float a3 = A[72 + ijk4];
        float a2 = A[8 + i4 * 8 + j4];
        float a1 = A[i4];
        float c4v[4];
#pragma unroll
        for (int m = 0; m < 4; ++m) {
            int l = l0 + m;
            float t = A[584 + ijk4 * 8 + l] + B[584 + ijk4 * 8 + l];
            t = fmaf(a3, B[l], t);
            t = fmaf(a2, B[8 + k4 * 8 + l], t);
            t = fmaf(a1, B[72 + j4 * 64 + k4 * 8 + l], t);
            c4v[m] = t;
        }
        float n3 = 0.f, n2 = 0.f, n1 = 0.f;
        if (tid < 512) {
            int ii = tid >> 6, jj = (tid >> 3) & 7, kk = tid & 7;
            n3 = A[72 + tid] + B[72 + tid];
            n3 = fmaf(A[8 + ii * 8 + jj], B[kk], n3);
            n3 = fmaf(A[ii], B[8 + jj * 8 + kk], n3);
        }
        if (tid < 64) {
            int ii = tid >> 3, jj = tid & 7;
            n2 = A[8 + tid] + B[8 + tid] + A[ii] * B[jj];
        }
        if (tid < 8) n1 = A[tid] + B[tid];
        __syncthreads();   // all reads of sig[0] complete

        float* W = sig[0];
#pragma unroll
        for (int m = 0; m < 4; ++m) W[584 + ijk4 * 8 + l0 + m] = c4v[m];
        if (tid < 512) W[72 + tid] = n3;
        if (tid < 64) W[8 + tid] = n2;
        if (tid < 8) W[tid] = n1;
        __syncthreads();
    }

    // ---- coalesced write-out ----
    float* o = out + (size_t)n * OUT_PER;
    for (int idx = tid; idx < OUT_PER; idx += 1024) o[idx] = sig[0][idx];
}

extern "C" void kernel_launch(void* const* d_in, const int* in_sizes, int n_in,
                              void* d_out, int out_size, void* d_ws, size_t ws_size,
                              hipStream_t stream) {
    const float* path = (const float*)d_in[0];
    float* out = (float*)d_out;
    sig_kernel<<<N_SAMP, 1024, 0, stream>>>(path, out);
}